// Round 1
// baseline (454.350 us; speedup 1.0000x reference)
//
#include <hip/hip_runtime.h>
#include <stdint.h>
#include <stddef.h>

// ThresholdMoE: out = sum_e w[n,e] * (x @ A_e) @ B_e, w = renorm(softmax(x@gw+b) >= 0.1)
// N=65536 tokens, D=1024, E=8, R=64, ER=512.
// Strategy: fp32 gate (exact) + two bf16 MFMA GEMMs with fragment-packed operands.

typedef float f32x4 __attribute__((ext_vector_type(4)));
typedef short bf16x8 __attribute__((ext_vector_type(8)));

#define MFMA_16x16x32(A, B, C) __builtin_amdgcn_mfma_f32_16x16x32_bf16((A), (B), (C), 0, 0, 0)

__device__ __forceinline__ unsigned short f2bf(float f) {
    union { float f; unsigned int u; } v;
    v.f = f;
    unsigned int u = v.u;
    u += 0x7FFFu + ((u >> 16) & 1u);   // RNE
    return (unsigned short)(u >> 16);
}

__device__ __forceinline__ void load16_lds(unsigned short* lds, const unsigned short* g) {
    __builtin_amdgcn_global_load_lds(
        (const __attribute__((address_space(1))) unsigned int*)g,
        (__attribute__((address_space(3))) unsigned int*)lds, 16, 0, 0);
}

// ---------------------------------------------------------------------------
// Pack lora_A / lora_B to bf16 in MFMA B-fragment order.
// A_P: [D/32=32][ER/16=32][lane 64][j 8], element = A_cat[d][e*64+r],
//      d = kblk*32 + (l>>4)*8 + j, col = cblk*16 + (l&15)
// B_P: [ER/32=16][D/16=64][lane 64][j 8], element = B_cat[e*64+r][d]
// ---------------------------------------------------------------------------
__global__ __launch_bounds__(256) void convert_pack(
        const float* __restrict__ LA, const float* __restrict__ LB,
        unsigned short* __restrict__ A_P, unsigned short* __restrict__ B_P) {
    int gid = blockIdx.x * 256 + threadIdx.x;          // 0 .. 1048575
    if (gid < 524288) {
        int j = gid & 7, l = (gid >> 3) & 63, cblk = (gid >> 9) & 31, kblk = gid >> 14;
        int d = kblk * 32 + (l >> 4) * 8 + j;
        int col = cblk * 16 + (l & 15);
        int e = col >> 6, r = col & 63;
        A_P[gid] = f2bf(LA[((size_t)e * 1024 + d) * 64 + r]);   // lora_A[e][d][r]
    } else {
        int idx = gid - 524288;
        int j = idx & 7, l = (idx >> 3) & 63, cblk = (idx >> 9) & 63, kblk = idx >> 15;
        int k = kblk * 32 + (l >> 4) * 8 + j;          // index into ER
        int d = cblk * 16 + (l & 15);
        int e = k >> 6, r = k & 63;
        B_P[idx] = f2bf(LB[((size_t)e * 64 + r) * 1024 + d]);   // lora_B[e][r][d]
    }
}

// ---------------------------------------------------------------------------
// Gate: fp32, exact. 8 threads per token; each covers k = sub*4..+3 (+32*it).
// Coalesced: 8 consecutive threads read 128B contiguous of one row.
// ---------------------------------------------------------------------------
__global__ __launch_bounds__(256) void gate_kernel(
        const float* __restrict__ X, const float* __restrict__ GW,
        const float* __restrict__ GB, float* __restrict__ Wg) {
    int tid = threadIdx.x;
    int tok = blockIdx.x * 32 + (tid >> 3);
    int sub = tid & 7;
    const float* xrow = X + (size_t)tok * 1024;
    float lg[8];
#pragma unroll
    for (int e = 0; e < 8; ++e) lg[e] = 0.f;
    for (int it = 0; it < 32; ++it) {
        int k0 = it * 32 + sub * 4;
        f32x4 x = *(const f32x4*)(xrow + k0);
#pragma unroll
        for (int jj = 0; jj < 4; ++jj) {
            const f32x4* gp = (const f32x4*)(GW + (size_t)(k0 + jj) * 8);
            f32x4 g0 = gp[0], g1 = gp[1];
            float xv = x[jj];
            lg[0] += xv * g0[0]; lg[1] += xv * g0[1];
            lg[2] += xv * g0[2]; lg[3] += xv * g0[3];
            lg[4] += xv * g1[0]; lg[5] += xv * g1[1];
            lg[6] += xv * g1[2]; lg[7] += xv * g1[3];
        }
    }
#pragma unroll
    for (int s = 1; s < 8; s <<= 1) {
#pragma unroll
        for (int e = 0; e < 8; ++e) lg[e] += __shfl_xor(lg[e], s, 8);
    }
    if (sub == 0) {
        float p[8], m = -1e30f, ssum = 0.f;
#pragma unroll
        for (int e = 0; e < 8; ++e) { lg[e] += GB[e]; m = fmaxf(m, lg[e]); }
#pragma unroll
        for (int e = 0; e < 8; ++e) { p[e] = expf(lg[e] - m); ssum += p[e]; }
        float inv = 1.f / ssum;
        float w[8], ws = 0.f;
#pragma unroll
        for (int e = 0; e < 8; ++e) {
            float pe = p[e] * inv;
            w[e] = (pe >= 0.1f) ? pe : 0.f;
            ws += w[e];
        }
        if (ws == 0.f) ws = 1.f;
        float invw = 1.f / ws;
        float* o = Wg + (size_t)tok * 8;
#pragma unroll
        for (int e = 0; e < 8; ++e) o[e] = w[e] * invw;
    }
}

// ---------------------------------------------------------------------------
// Stage 1: H[n, e*64+r] = w[n,e] * (x @ A_cat), bf16 out in kernel-2-A-frag
// packed order. 64 tokens/block, 8 waves; wave w owns H cols [w*64, w*64+64)
// => expert index == wave id (weight scale is wave-uniform in e).
// ---------------------------------------------------------------------------
__global__ __launch_bounds__(512, 4) void stage1_kernel(
        const float* __restrict__ X, const unsigned short* __restrict__ A_P,
        const float* __restrict__ Wg, unsigned short* __restrict__ H_P) {
    __shared__ union SM1 {
        struct {
            unsigned short x[64 * 40];   // [64 rows][32 + 8 pad] bf16, 5120B
            unsigned short a[32 * 512];  // packed A tile, 32KB
        } p1;
        unsigned short hb[64 * 520];     // H bounce [64][512+8 pad], 66560B
    } sm;
    __shared__ float wl[512];            // weights [64 tok][8 e]

    int tid = threadIdx.x;
    int lane = tid & 63;
    int w = tid >> 6;                    // wave 0..7 == expert id
    int blk = blockIdx.x;                // token rows blk*64 .. +63

    wl[tid] = Wg[(size_t)blk * 512 + tid];

    const float* xp = X + (size_t)blk * 64 * 1024 + (size_t)(tid >> 3) * 1024 + (tid & 7) * 4;
    unsigned short* xw = &sm.p1.x[(tid >> 3) * 40 + (tid & 7) * 4];

    f32x4 acc[4][4] = {};
    for (int kb = 0; kb < 32; ++kb) {
        f32x4 xv = *(const f32x4*)(xp + kb * 32);
        const unsigned short* asrc = A_P + (size_t)kb * 16384 + tid * 8;
#pragma unroll
        for (int i = 0; i < 4; ++i)
            load16_lds(&sm.p1.a[tid * 8 + i * 4096], asrc + i * 4096);
        unsigned int lo = (unsigned int)f2bf(xv[0]) | ((unsigned int)f2bf(xv[1]) << 16);
        unsigned int hi = (unsigned int)f2bf(xv[2]) | ((unsigned int)f2bf(xv[3]) << 16);
        *((uint2*)xw) = make_uint2(lo, hi);
        __syncthreads();
        bf16x8 af[4], bv[4];
#pragma unroll
        for (int m = 0; m < 4; ++m)
            af[m] = *(const bf16x8*)&sm.p1.x[(m * 16 + (lane & 15)) * 40 + (lane >> 4) * 8];
#pragma unroll
        for (int n = 0; n < 4; ++n)
            bv[n] = *(const bf16x8*)&sm.p1.a[(w * 4 + n) * 512 + lane * 8];
#pragma unroll
        for (int m = 0; m < 4; ++m)
#pragma unroll
            for (int n = 0; n < 4; ++n)
                acc[m][n] = MFMA_16x16x32(af[m], bv[n], acc[m][n]);
        __syncthreads();
    }

    // epilogue: scale by weight, bf16, bounce through LDS to A-frag packing
#pragma unroll
    for (int m = 0; m < 4; ++m) {
        float wv[4];
#pragma unroll
        for (int r = 0; r < 4; ++r)
            wv[r] = wl[(m * 16 + (lane >> 4) * 4 + r) * 8 + w];
#pragma unroll
        for (int n = 0; n < 4; ++n) {
            int col = w * 64 + n * 16 + (lane & 15);
#pragma unroll
            for (int r = 0; r < 4; ++r) {
                int row = m * 16 + (lane >> 4) * 4 + r;
                sm.hb[row * 520 + col] = f2bf(acc[m][n][r] * wv[r]);
            }
        }
    }
    __syncthreads();
    // H_P: [N/16][ER/32=16][lane 64][j 8]
#pragma unroll
    for (int it = 0; it < 8; ++it) {
        int gi = tid + it * 512;
        int ft = gi >> 6;                 // fragtile 0..63
        int l2 = gi & 63;
        int rowblk = ft >> 4;             // 0..3
        int kblk = ft & 15;               // 0..15
        int row = rowblk * 16 + (l2 & 15);
        int cs = kblk * 32 + (l2 >> 4) * 8;
        uint4 v = *(const uint4*)&sm.hb[row * 520 + cs];
        *(uint4*)&H_P[(((size_t)blk * 4 + rowblk) * 16 + kblk) * 512 + l2 * 8] = v;
    }
}

// ---------------------------------------------------------------------------
// Stage 2: out[N,1024] = H @ B_cat, fp32 out. Tile 128x256, 8 waves (2x4),
// K=512. All staging via global_load_lds (linear), all ds_reads consecutive.
// Grid swizzled so the 4 col-tiles of a row-panel run back-to-back on one XCD.
// ---------------------------------------------------------------------------
__global__ __launch_bounds__(512, 4) void stage2_kernel(
        const unsigned short* __restrict__ H_P, const unsigned short* __restrict__ B_P,
        float* __restrict__ Out) {
    __shared__ unsigned short a_lds[8 * 512];    // 8KB  [rowblk 8][lane 64][8]
    __shared__ unsigned short b_lds[16 * 512];   // 16KB [cblk 16][lane 64][8]

    int tid = threadIdx.x;
    int lane = tid & 63;
    int wid = tid >> 6;
    int wr = wid >> 2, wc = wid & 3;
    int bw = blockIdx.x;                          // 2048 blocks
    int mt = ((bw >> 5) << 3) | (bw & 7);         // 0..511  (XCD = mt & 7)
    int nt = (bw >> 3) & 3;                       // 0..3

    f32x4 acc[4][4] = {};
    for (int kc = 0; kc < 16; ++kc) {
        load16_lds(&a_lds[tid * 8],
                   H_P + (((size_t)mt * 8 + (tid >> 6)) * 16 + kc) * 512 + (tid & 63) * 8);
        const unsigned short* bsrc = B_P + ((size_t)kc * 64 + nt * 16) * 512 + tid * 8;
        load16_lds(&b_lds[tid * 8], bsrc);
        load16_lds(&b_lds[tid * 8 + 4096], bsrc + 4096);
        __syncthreads();
        bf16x8 af[4], bv[4];
#pragma unroll
        for (int m = 0; m < 4; ++m)
            af[m] = *(const bf16x8*)&a_lds[(wr * 4 + m) * 512 + lane * 8];
#pragma unroll
        for (int n = 0; n < 4; ++n)
            bv[n] = *(const bf16x8*)&b_lds[(wc * 4 + n) * 512 + lane * 8];
#pragma unroll
        for (int m = 0; m < 4; ++m)
#pragma unroll
            for (int n = 0; n < 4; ++n)
                acc[m][n] = MFMA_16x16x32(af[m], bv[n], acc[m][n]);
        __syncthreads();
    }

    size_t rb = (size_t)mt * 128 + wr * 64;
    int cb = nt * 256 + wc * 64;
#pragma unroll
    for (int m = 0; m < 4; ++m)
#pragma unroll
        for (int n = 0; n < 4; ++n) {
            int col = cb + n * 16 + (lane & 15);
#pragma unroll
            for (int r = 0; r < 4; ++r) {
                size_t row = rb + m * 16 + (lane >> 4) * 4 + r;
                Out[row * 1024 + col] = acc[m][n][r];
            }
        }
}

// ---------------------------------------------------------------------------
extern "C" void kernel_launch(void* const* d_in, const int* in_sizes, int n_in,
                              void* d_out, int out_size, void* d_ws, size_t ws_size,
                              hipStream_t stream) {
    const float* X  = (const float*)d_in[0];   // [65536][1024]
    const float* GW = (const float*)d_in[1];   // [1024][8]
    const float* GB = (const float*)d_in[2];   // [8]
    const float* LA = (const float*)d_in[3];   // [8][1024][64]
    const float* LB = (const float*)d_in[4];   // [8][64][1024]
    float* Out = (float*)d_out;                // [65536][1024]

    char* ws = (char*)d_ws;
    float*          Wg  = (float*)ws;                              // 2MB  weights [N][8]
    unsigned short* A_P = (unsigned short*)(ws + (2u << 20));      // 1MB  packed lora_A
    unsigned short* B_P = (unsigned short*)(ws + (3u << 20));      // 1MB  packed lora_B
    unsigned short* H_P = (unsigned short*)(ws + (4u << 20));      // 64MB packed H

    convert_pack<<<4096, 256, 0, stream>>>(LA, LB, A_P, B_P);
    gate_kernel<<<2048, 256, 0, stream>>>(X, GW, GB, Wg);
    stage1_kernel<<<1024, 512, 0, stream>>>(X, A_P, Wg, H_P);
    stage2_kernel<<<2048, 512, 0, stream>>>(H_P, B_P, Out);
}

// Round 2
// 412.583 us; speedup vs baseline: 1.1012x; 1.1012x over previous
//
#include <hip/hip_runtime.h>
#include <stdint.h>
#include <stddef.h>

// ThresholdMoE: out = sum_e w[n,e] * (x @ A_e) @ B_e, w = renorm(softmax(x@gw+b) >= 0.1)
// N=65536 tokens, D=1024, E=8, R=64, ER=512.
// R2: gate fused into stage1 (X read once); fp32 gate numerics identical to R1.

typedef float f32x4 __attribute__((ext_vector_type(4)));
typedef short bf16x8 __attribute__((ext_vector_type(8)));

#define MFMA_16x16x32(A, B, C) __builtin_amdgcn_mfma_f32_16x16x32_bf16((A), (B), (C), 0, 0, 0)

__device__ __forceinline__ unsigned short f2bf(float f) {
    union { float f; unsigned int u; } v;
    v.f = f;
    unsigned int u = v.u;
    u += 0x7FFFu + ((u >> 16) & 1u);   // RNE
    return (unsigned short)(u >> 16);
}

__device__ __forceinline__ void load16_lds(unsigned short* lds, const unsigned short* g) {
    __builtin_amdgcn_global_load_lds(
        (const __attribute__((address_space(1))) unsigned int*)g,
        (__attribute__((address_space(3))) unsigned int*)lds, 16, 0, 0);
}

// ---------------------------------------------------------------------------
// Pack lora_A / lora_B to bf16 in MFMA B-fragment order.
// A_P: [D/32=32][ER/16=32][lane 64][j 8], element = A_cat[d][e*64+r],
//      d = kblk*32 + (l>>4)*8 + j, col = cblk*16 + (l&15)
// B_P: [ER/32=16][D/16=64][lane 64][j 8], element = B_cat[e*64+r][d]
// ---------------------------------------------------------------------------
__global__ __launch_bounds__(256) void convert_pack(
        const float* __restrict__ LA, const float* __restrict__ LB,
        unsigned short* __restrict__ A_P, unsigned short* __restrict__ B_P) {
    int gid = blockIdx.x * 256 + threadIdx.x;          // 0 .. 1048575
    if (gid < 524288) {
        int j = gid & 7, l = (gid >> 3) & 63, cblk = (gid >> 9) & 31, kblk = gid >> 14;
        int d = kblk * 32 + (l >> 4) * 8 + j;
        int col = cblk * 16 + (l & 15);
        int e = col >> 6, r = col & 63;
        A_P[gid] = f2bf(LA[((size_t)e * 1024 + d) * 64 + r]);   // lora_A[e][d][r]
    } else {
        int idx = gid - 524288;
        int j = idx & 7, l = (idx >> 3) & 63, cblk = (idx >> 9) & 63, kblk = idx >> 15;
        int k = kblk * 32 + (l >> 4) * 8 + j;          // index into ER
        int d = cblk * 16 + (l & 15);
        int e = k >> 6, r = k & 63;
        B_P[idx] = f2bf(LB[((size_t)e * 64 + r) * 1024 + d]);   // lora_B[e][r][d]
    }
}

// ---------------------------------------------------------------------------
// Stage 1 (gate fused): H[n, e*64+r] = w[n,e] * (x @ A_cat), bf16 out in
// kernel-2-A-frag packed order. 64 tokens/block, 8 waves; wave w owns expert w.
// While staging X, each thread accumulates its 8 gate logits in fp32 over
// cols {kb*32 + sub*4 .. +3}; post-loop 8-lane butterfly + softmax/threshold.
// ---------------------------------------------------------------------------
__global__ __launch_bounds__(512, 4) void stage1_kernel(
        const float* __restrict__ X, const unsigned short* __restrict__ A_P,
        const float* __restrict__ GW, const float* __restrict__ GB,
        unsigned short* __restrict__ H_P) {
    __shared__ union SM1 {
        struct {
            unsigned short x[64 * 40];   // [64 rows][32 + 8 pad] bf16, 5120B
            unsigned short a[32 * 512];  // packed A tile, 32KB
        } p1;
        unsigned short hb[64 * 520];     // H bounce [64][512+8 pad], 66560B
    } sm;
    __shared__ float wl[512];            // weights [64 tok][8 e]

    int tid = threadIdx.x;
    int lane = tid & 63;
    int w = tid >> 6;                    // wave 0..7 == expert id
    int blk = blockIdx.x;                // token rows blk*64 .. +63
    int row = tid >> 3;                  // 0..63 (X staging row)
    int sub = tid & 7;

    const float* xp = X + (size_t)blk * 64 * 1024 + (size_t)row * 1024 + sub * 4;
    unsigned short* xw = &sm.p1.x[row * 40 + sub * 4];

    float lg[8];
#pragma unroll
    for (int e = 0; e < 8; ++e) lg[e] = 0.f;

    f32x4 acc[4][4] = {};
    for (int kb = 0; kb < 32; ++kb) {
        f32x4 xv = *(const f32x4*)(xp + kb * 32);
        const unsigned short* asrc = A_P + (size_t)kb * 16384 + tid * 8;
#pragma unroll
        for (int i = 0; i < 4; ++i)
            load16_lds(&sm.p1.a[tid * 8 + i * 4096], asrc + i * 4096);
        // fused gate accumulation (fp32, same partition as R1 gate kernel)
#pragma unroll
        for (int jj = 0; jj < 4; ++jj) {
            const f32x4* gp = (const f32x4*)(GW + (size_t)(kb * 32 + sub * 4 + jj) * 8);
            f32x4 g0 = gp[0], g1 = gp[1];
            float xvj = xv[jj];
            lg[0] += xvj * g0[0]; lg[1] += xvj * g0[1];
            lg[2] += xvj * g0[2]; lg[3] += xvj * g0[3];
            lg[4] += xvj * g1[0]; lg[5] += xvj * g1[1];
            lg[6] += xvj * g1[2]; lg[7] += xvj * g1[3];
        }
        unsigned int lo = (unsigned int)f2bf(xv[0]) | ((unsigned int)f2bf(xv[1]) << 16);
        unsigned int hi = (unsigned int)f2bf(xv[2]) | ((unsigned int)f2bf(xv[3]) << 16);
        *((uint2*)xw) = make_uint2(lo, hi);
        __syncthreads();
        bf16x8 af[4], bv[4];
#pragma unroll
        for (int m = 0; m < 4; ++m)
            af[m] = *(const bf16x8*)&sm.p1.x[(m * 16 + (lane & 15)) * 40 + (lane >> 4) * 8];
#pragma unroll
        for (int n = 0; n < 4; ++n)
            bv[n] = *(const bf16x8*)&sm.p1.a[(w * 4 + n) * 512 + lane * 8];
#pragma unroll
        for (int m = 0; m < 4; ++m)
#pragma unroll
            for (int n = 0; n < 4; ++n)
                acc[m][n] = MFMA_16x16x32(af[m], bv[n], acc[m][n]);
        __syncthreads();
    }

    // gate finish: butterfly over the 8 threads sharing a row (same wave)
#pragma unroll
    for (int s = 1; s < 8; s <<= 1) {
#pragma unroll
        for (int e = 0; e < 8; ++e) lg[e] += __shfl_xor(lg[e], s, 8);
    }
    {
        float p[8], m = -1e30f, ssum = 0.f;
#pragma unroll
        for (int e = 0; e < 8; ++e) { lg[e] += GB[e]; m = fmaxf(m, lg[e]); }
#pragma unroll
        for (int e = 0; e < 8; ++e) { p[e] = expf(lg[e] - m); ssum += p[e]; }
        float inv = 1.f / ssum;
        float wv[8], wsum = 0.f;
#pragma unroll
        for (int e = 0; e < 8; ++e) {
            float pe = p[e] * inv;
            wv[e] = (pe >= 0.1f) ? pe : 0.f;
            wsum += wv[e];
        }
        if (wsum == 0.f) wsum = 1.f;
        float invw = 1.f / wsum;
        wl[row * 8 + sub] = wv[sub] * invw;   // each of the 8 threads writes one e
    }
    __syncthreads();

    // epilogue: scale by weight, bf16, bounce through LDS to A-frag packing
#pragma unroll
    for (int m = 0; m < 4; ++m) {
        float wv[4];
#pragma unroll
        for (int r = 0; r < 4; ++r)
            wv[r] = wl[(m * 16 + (lane >> 4) * 4 + r) * 8 + w];
#pragma unroll
        for (int n = 0; n < 4; ++n) {
            int col = w * 64 + n * 16 + (lane & 15);
#pragma unroll
            for (int r = 0; r < 4; ++r) {
                int rr = m * 16 + (lane >> 4) * 4 + r;
                sm.hb[rr * 520 + col] = f2bf(acc[m][n][r] * wv[r]);
            }
        }
    }
    __syncthreads();
    // H_P: [N/16][ER/32=16][lane 64][j 8]
#pragma unroll
    for (int it = 0; it < 8; ++it) {
        int gi = tid + it * 512;
        int ft = gi >> 6;                 // fragtile 0..63
        int l2 = gi & 63;
        int rowblk = ft >> 4;             // 0..3
        int kblk = ft & 15;               // 0..15
        int rr = rowblk * 16 + (l2 & 15);
        int cs = kblk * 32 + (l2 >> 4) * 8;
        uint4 v = *(const uint4*)&sm.hb[rr * 520 + cs];
        *(uint4*)&H_P[(((size_t)blk * 4 + rowblk) * 16 + kblk) * 512 + l2 * 8] = v;
    }
}

// ---------------------------------------------------------------------------
// Stage 2: out[N,1024] = H @ B_cat, fp32 out. Tile 128x256, 8 waves (2x4),
// K=512. All staging via global_load_lds (linear), all ds_reads consecutive.
// Grid swizzled so the 4 col-tiles of a row-panel run back-to-back on one XCD.
// ---------------------------------------------------------------------------
__global__ __launch_bounds__(512, 4) void stage2_kernel(
        const unsigned short* __restrict__ H_P, const unsigned short* __restrict__ B_P,
        float* __restrict__ Out) {
    __shared__ unsigned short a_lds[8 * 512];    // 8KB  [rowblk 8][lane 64][8]
    __shared__ unsigned short b_lds[16 * 512];   // 16KB [cblk 16][lane 64][8]

    int tid = threadIdx.x;
    int lane = tid & 63;
    int wid = tid >> 6;
    int wr = wid >> 2, wc = wid & 3;
    int bw = blockIdx.x;                          // 2048 blocks
    int mt = ((bw >> 5) << 3) | (bw & 7);         // 0..511  (XCD = mt & 7)
    int nt = (bw >> 3) & 3;                       // 0..3

    f32x4 acc[4][4] = {};
    for (int kc = 0; kc < 16; ++kc) {
        load16_lds(&a_lds[tid * 8],
                   H_P + (((size_t)mt * 8 + (tid >> 6)) * 16 + kc) * 512 + (tid & 63) * 8);
        const unsigned short* bsrc = B_P + ((size_t)kc * 64 + nt * 16) * 512 + tid * 8;
        load16_lds(&b_lds[tid * 8], bsrc);
        load16_lds(&b_lds[tid * 8 + 4096], bsrc + 4096);
        __syncthreads();
        bf16x8 af[4], bv[4];
#pragma unroll
        for (int m = 0; m < 4; ++m)
            af[m] = *(const bf16x8*)&a_lds[(wr * 4 + m) * 512 + lane * 8];
#pragma unroll
        for (int n = 0; n < 4; ++n)
            bv[n] = *(const bf16x8*)&b_lds[(wc * 4 + n) * 512 + lane * 8];
#pragma unroll
        for (int m = 0; m < 4; ++m)
#pragma unroll
            for (int n = 0; n < 4; ++n)
                acc[m][n] = MFMA_16x16x32(af[m], bv[n], acc[m][n]);
        __syncthreads();
    }

    size_t rb = (size_t)mt * 128 + wr * 64;
    int cb = nt * 256 + wc * 64;
#pragma unroll
    for (int m = 0; m < 4; ++m)
#pragma unroll
        for (int n = 0; n < 4; ++n) {
            int col = cb + n * 16 + (lane & 15);
#pragma unroll
            for (int r = 0; r < 4; ++r) {
                size_t row = rb + m * 16 + (lane >> 4) * 4 + r;
                Out[row * 1024 + col] = acc[m][n][r];
            }
        }
}

// ---------------------------------------------------------------------------
extern "C" void kernel_launch(void* const* d_in, const int* in_sizes, int n_in,
                              void* d_out, int out_size, void* d_ws, size_t ws_size,
                              hipStream_t stream) {
    const float* X  = (const float*)d_in[0];   // [65536][1024]
    const float* GW = (const float*)d_in[1];   // [1024][8]
    const float* GB = (const float*)d_in[2];   // [8]
    const float* LA = (const float*)d_in[3];   // [8][1024][64]
    const float* LB = (const float*)d_in[4];   // [8][64][1024]
    float* Out = (float*)d_out;                // [65536][1024]

    char* ws = (char*)d_ws;
    unsigned short* A_P = (unsigned short*)ws;                     // 1MB  packed lora_A
    unsigned short* B_P = (unsigned short*)(ws + (1u << 20));      // 1MB  packed lora_B
    unsigned short* H_P = (unsigned short*)(ws + (2u << 20));      // 64MB packed H

    convert_pack<<<4096, 256, 0, stream>>>(LA, LB, A_P, B_P);
    stage1_kernel<<<1024, 512, 0, stream>>>(X, A_P, GW, GB, H_P);
    stage2_kernel<<<2048, 512, 0, stream>>>(H_P, B_P, Out);
}